// Round 10
// baseline (1244.482 us; speedup 1.0000x reference)
//
#include <hip/hip_runtime.h>
#include <hip/hip_bf16.h>
#include <hip/hip_fp16.h>

// Problem constants (reference: OUT=11008, IN=4096, B=2, S=2048)
#define K_DIM 4096
#define N_DIM 11008
#define M_DIM 4096  // B*S

typedef _Float16 f16x8 __attribute__((ext_vector_type(8)));
typedef float f32x4 __attribute__((ext_vector_type(4)));

typedef const __attribute__((address_space(1))) void* gas_cptr;
typedef __attribute__((address_space(3))) void* las_ptr;

__device__ __forceinline__ void gload_lds16(const void* g, void* l) {
  __builtin_amdgcn_global_load_lds((gas_cptr)g, (las_ptr)l, 16, 0, 0);
}

// ---------------------------------------------------------------------------
// Dequant via per-row LUT (r9, proven): 256 curve values per row in LDS,
// then vectorized gather. 16x fewer powf -> memory-bound.
// ---------------------------------------------------------------------------
__global__ __launch_bounds__(256) void dequant_kernel(
    const int* __restrict__ mag, const int* __restrict__ sgn,
    const float* __restrict__ scales, const float* __restrict__ alphas,
    const float* __restrict__ powers, const float* __restrict__ divisors,
    _Float16* __restrict__ Wh) {
  __shared__ float tbl[256];
  const int o = blockIdx.x;   // row
  const int t = threadIdx.x;
  {
    float sc = scales[o];
    float al = alphas[o];
    float p = powers[o];
    float idv = 1.0f / divisors[o];
    float xn = (float)t * idv;
    float pw = __powf(xn, p);  // t==0 -> 0
    tbl[t] = sc * (al * xn + (1.0f - al) * pw);
  }
  __syncthreads();

  const size_t base = (size_t)o * K_DIM + (size_t)t * 16;
  const int4* mp = (const int4*)(mag + base);
  const int4* sp = (const int4*)(sgn + base);
  int4 m0 = mp[0], m1 = mp[1], m2 = mp[2], m3 = mp[3];
  int4 s0 = sp[0], s1 = sp[1], s2 = sp[2], s3 = sp[3];

  int mi[16] = {m0.x, m0.y, m0.z, m0.w, m1.x, m1.y, m1.z, m1.w,
                m2.x, m2.y, m2.z, m2.w, m3.x, m3.y, m3.z, m3.w};
  int si[16] = {s0.x, s0.y, s0.z, s0.w, s1.x, s1.y, s1.z, s1.w,
                s2.x, s2.y, s2.z, s2.w, s3.x, s3.y, s3.z, s3.w};

  f16x8 oa, ob;
#pragma unroll
  for (int e = 0; e < 8; ++e) oa[e] = (_Float16)((float)si[e] * tbl[mi[e]]);
#pragma unroll
  for (int e = 0; e < 8; ++e) ob[e] = (_Float16)((float)si[8 + e] * tbl[mi[8 + e]]);
  *(f16x8*)&Wh[base] = oa;
  *(f16x8*)&Wh[base + 8] = ob;
}

// ---------------------------------------------------------------------------
// x (fp32) -> fp16
// ---------------------------------------------------------------------------
__global__ __launch_bounds__(256) void xconv_kernel(const float* __restrict__ x,
                                                    _Float16* __restrict__ xh) {
  int v = blockIdx.x * 256 + threadIdx.x;
  int base = v * 8;
  float4 a = *(const float4*)(x + base);
  float4 b = *(const float4*)(x + base + 4);
  f16x8 o;
  o[0] = (_Float16)a.x; o[1] = (_Float16)a.y;
  o[2] = (_Float16)a.z; o[3] = (_Float16)a.w;
  o[4] = (_Float16)b.x; o[5] = (_Float16)b.y;
  o[6] = (_Float16)b.z; o[7] = (_Float16)b.w;
  *(f16x8*)&xh[base] = o;
}

// ---------------------------------------------------------------------------
// 256x256 GEMM_BT, BK=64, PRODUCER/CONSUMER wave specialization.
// 576 threads = 8 consumer waves (2x4 of 128x64 tiles, 16x16x32 f16 MFMA)
//             + 1 producer wave (stages all 64 gload_lds of tile t+1).
// Consumers NEVER touch vmcnt: pure {ds_read, counted lgkmcnt, MFMA} (r8's
// proven tile body). Producer's VMC(0) (~900cy HBM) hides under consumers'
// ~2500cy compute. ONE s_barrier per K-tile for cross-role handoff.
// WAR: producer writes buf[(t+1)&1], consumers read buf[t&1]; consumer reads
// all lgkm-retired before tile-end BAR; producer VMC(0) before BAR makes its
// stages visible. Barrier count (NT+1) identical on both paths.
// Swizzle (T2, 0 conflicts r4/r6/r8/r9): colbyte ^= ((row>>1)&3)<<4,
// pre-applied on the global source, applied on the ds_read address.
// ---------------------------------------------------------------------------
#define BM 256
#define BN 256
#define BK 64
#define NT (K_DIM / BK)   // 64
#define NBN (N_DIM / BN)  // 43
#define NBM (M_DIM / BM)  // 16

#define BAR() __builtin_amdgcn_s_barrier()
#define SBAR() __builtin_amdgcn_sched_barrier(0)
#define LGKMC(N)                                              \
  asm volatile("s_waitcnt lgkmcnt(" #N ")" ::: "memory");     \
  __builtin_amdgcn_sched_barrier(0)
#define VMC(N) asm volatile("s_waitcnt vmcnt(" #N ")" ::: "memory")

#define RD_A(dst_, buf_, kh_, qm_)                                       \
  _Pragma("unroll") for (int m = 0; m < 4; ++m)                          \
      dst_[m] = *(const f16x8*)&lds[buf_][kh_][aoff + ((qm_)*4 + m) * 512];

#define RD_B(dst_, buf_, kh_)                                            \
  _Pragma("unroll") for (int n = 0; n < 4; ++n)                          \
      dst_[n] = *(const f16x8*)&lds[buf_][2 + (kh_)][boff + n * 512];

#define MFMA16(a_, b_, qm_)                                              \
  do {                                                                   \
    __builtin_amdgcn_s_setprio(1);                                       \
    _Pragma("unroll") for (int i = 0; i < 4; ++i)                        \
        _Pragma("unroll") for (int j = 0; j < 4; ++j)                    \
            acc[(qm_)*4 + i][j] = __builtin_amdgcn_mfma_f32_16x16x32_f16(\
                a_[i], b_[j], acc[(qm_)*4 + i][j], 0, 0, 0);             \
    __builtin_amdgcn_s_setprio(0);                                       \
  } while (0)

// Consumer K-tile: r8's register-pipelined body (proven correct), no vmcnt.
#define COMPUTE_TILE(buf_)                                               \
  do {                                                                   \
    RD_A(aX, buf_, 0, 0);                                                \
    RD_B(bX, buf_, 0);                                                   \
    LGKMC(0);                                                            \
    RD_A(aY, buf_, 0, 1);                                                \
    SBAR();                                                              \
    MFMA16(aX, bX, 0);                                                   \
    RD_A(aX, buf_, 1, 0);                                                \
    RD_B(bY, buf_, 1);                                                   \
    SBAR();                                                              \
    LGKMC(8);                                                            \
    MFMA16(aY, bX, 1);                                                   \
    RD_A(aY, buf_, 1, 1);                                                \
    SBAR();                                                              \
    LGKMC(4);                                                            \
    MFMA16(aX, bY, 0);                                                   \
    LGKMC(0);                                                            \
    MFMA16(aY, bY, 1);                                                   \
  } while (0)

// Producer: stage one full K-tile (A kh0/kh1, B kh0/kh1) = 64 gload_lds.
// gload i covers region rows i*16..i*16+15 (same lane->row/col map and
// swizzle as the r4 512-thread staging; verified identical geometry).
#define STAGE_FULL(buf_, t_)                                             \
  _Pragma("unroll") for (int i = 0; i < 16; ++i) {                       \
    const _Float16* a_ = pA + (size_t)(i * 16) * K_DIM + (size_t)(t_)*BK;\
    const _Float16* b_ = pB + (size_t)(i * 16) * K_DIM + (size_t)(t_)*BK;\
    gload_lds16(a_,      &lds[buf_][0][i * 512]);                        \
    gload_lds16(a_ + 32, &lds[buf_][1][i * 512]);                        \
    gload_lds16(b_,      &lds[buf_][2][i * 512]);                        \
    gload_lds16(b_ + 32, &lds[buf_][3][i * 512]);                        \
  }

__global__ __launch_bounds__(576, 1) void gemm_kernel(
    const _Float16* __restrict__ A, const _Float16* __restrict__ Bt,
    float* __restrict__ C) {
  __shared__ _Float16 lds[2][4][8192];  // 128 KiB

  const int tid = threadIdx.x;
  const int lane = tid & 63;
  const int wave = tid >> 6;  // 0..8

  // XCD-aware swizzle (T1), bn-fastest (round-4 proven): 688 = 8 XCDs x 86
  const int bid = blockIdx.x;
  const int g = (bid & 7) * 86 + (bid >> 3);
  const int bm = g / NBN;
  const int bn = g - bm * NBN;
  const size_t row0 = (size_t)bm * BM;
  const size_t col0 = (size_t)bn * BN;

  if (wave == 8) {
    // ---------------- producer wave ----------------
    // lane -> (row within 16-row stripe, swizzled col): row = lane>>2,
    // colbyte = (lane&3)*16 ^ (((lane>>3)&3)<<4)   [== ((row>>1)&3)<<4]
    const int prow = lane >> 2;
    const int pcol = (((lane & 3) * 16) ^ (((lane >> 3) & 3) << 4)) >> 1;
    const _Float16* pA = A + (row0 + prow) * (size_t)K_DIM + pcol;
    const _Float16* pB = Bt + (col0 + prow) * (size_t)K_DIM + pcol;

    STAGE_FULL(0, 0);
    VMC(0);
    BAR();  // prologue barrier
    for (int t = 0; t < NT; ++t) {
      if (t < NT - 1) {
        STAGE_FULL((t + 1) & 1, t + 1);
        VMC(0);
      }
      BAR();  // tile-end barrier
    }
    return;
  }

  // ---------------- consumer waves (0..7) ----------------
  const int wm = wave >> 2;  // 0..1
  const int wn = wave & 3;   // 0..3

  // fragment read addressing (16x16x32: row=lane&15, kgrp=lane>>4)
  const int frow = lane & 15;
  const int fpcb = 16 * ((lane >> 4) ^ ((lane >> 1) & 3));  // swizzled col byte
  const int aoff = (wm * 128 + frow) * 32 + fpcb / 2;
  const int boff = (wn * 64 + frow) * 32 + fpcb / 2;

  f32x4 acc[8][4];
#pragma unroll
  for (int m = 0; m < 8; ++m)
#pragma unroll
    for (int n = 0; n < 4; ++n) acc[m][n] = (f32x4)0.0f;

  f16x8 aX[4], aY[4], bX[4], bY[4];

  BAR();  // prologue barrier (tile 0 staged)
  for (int t = 0; t < NT; ++t) {
    COMPUTE_TILE(t & 1);
    BAR();  // tile-end barrier
  }

  // epilogue: C/D layout col=lane&15, row=(lane>>4)*4+r
  const int crow = (lane >> 4) * 4;
  const int ccol = lane & 15;
  float* Cw = C + (row0 + wm * 128 + crow) * (size_t)N_DIM + col0 + wn * 64 + ccol;
#pragma unroll
  for (int m = 0; m < 8; ++m)
#pragma unroll
    for (int n = 0; n < 4; ++n)
#pragma unroll
      for (int r = 0; r < 4; ++r)
        Cw[(size_t)(m * 16 + r) * N_DIM + n * 16] = acc[m][n][r];
}

// ---------------------------------------------------------------------------
extern "C" void kernel_launch(void* const* d_in, const int* in_sizes, int n_in,
                              void* d_out, int out_size, void* d_ws, size_t ws_size,
                              hipStream_t stream) {
  const float* x = (const float*)d_in[0];
  const int* Wmag = (const int*)d_in[1];
  const int* Wsgn = (const int*)d_in[2];
  const float* scales = (const float*)d_in[3];
  const float* alphas = (const float*)d_in[4];
  const float* powers = (const float*)d_in[5];
  const float* divisors = (const float*)d_in[6];
  float* out = (float*)d_out;

  _Float16* xh = (_Float16*)d_ws;                        // 32 MB
  _Float16* Wh = xh + (size_t)M_DIM * K_DIM;             // 90 MB

  // 1) dequantize W -> fp16 [N][K]  (per-row LUT, one block per row)
  dequant_kernel<<<N_DIM, 256, 0, stream>>>(
      Wmag, Wsgn, scales, alphas, powers, divisors, Wh);
  // 2) x -> fp16 [M][K]
  {
    int nthreads_total = (M_DIM * K_DIM) / 8;
    xconv_kernel<<<nthreads_total / 256, 256, 0, stream>>>(x, xh);
  }
  // 3) GEMM: [M][K] x [N][K]^T -> [M][N] f32
  {
    dim3 grid(NBM * NBN);  // 688
    gemm_kernel<<<grid, 576, 0, stream>>>(xh, Wh, out);
  }
}

// Round 11
// 582.222 us; speedup vs baseline: 2.1375x; 2.1375x over previous
//
#include <hip/hip_runtime.h>
#include <hip/hip_bf16.h>
#include <hip/hip_fp16.h>

// Problem constants (reference: OUT=11008, IN=4096, B=2, S=2048)
#define K_DIM 4096
#define N_DIM 11008
#define M_DIM 4096  // B*S

typedef _Float16 f16x8 __attribute__((ext_vector_type(8)));
typedef float f32x4 __attribute__((ext_vector_type(4)));

typedef const __attribute__((address_space(1))) void* gas_cptr;
typedef __attribute__((address_space(3))) void* las_ptr;

__device__ __forceinline__ void gload_lds16(const void* g, void* l) {
  __builtin_amdgcn_global_load_lds((gas_cptr)g, (las_ptr)l, 16, 0, 0);
}

// ---------------------------------------------------------------------------
// Dequant via per-row LUT (r9, proven): 256 curve values per row in LDS,
// then vectorized gather. 16x fewer powf -> memory-bound.
// ---------------------------------------------------------------------------
__global__ __launch_bounds__(256) void dequant_kernel(
    const int* __restrict__ mag, const int* __restrict__ sgn,
    const float* __restrict__ scales, const float* __restrict__ alphas,
    const float* __restrict__ powers, const float* __restrict__ divisors,
    _Float16* __restrict__ Wh) {
  __shared__ float tbl[256];
  const int o = blockIdx.x;   // row
  const int t = threadIdx.x;
  {
    float sc = scales[o];
    float al = alphas[o];
    float p = powers[o];
    float idv = 1.0f / divisors[o];
    float xn = (float)t * idv;
    float pw = __powf(xn, p);  // t==0 -> 0
    tbl[t] = sc * (al * xn + (1.0f - al) * pw);
  }
  __syncthreads();

  const size_t base = (size_t)o * K_DIM + (size_t)t * 16;
  const int4* mp = (const int4*)(mag + base);
  const int4* sp = (const int4*)(sgn + base);
  int4 m0 = mp[0], m1 = mp[1], m2 = mp[2], m3 = mp[3];
  int4 s0 = sp[0], s1 = sp[1], s2 = sp[2], s3 = sp[3];

  int mi[16] = {m0.x, m0.y, m0.z, m0.w, m1.x, m1.y, m1.z, m1.w,
                m2.x, m2.y, m2.z, m2.w, m3.x, m3.y, m3.z, m3.w};
  int si[16] = {s0.x, s0.y, s0.z, s0.w, s1.x, s1.y, s1.z, s1.w,
                s2.x, s2.y, s2.z, s2.w, s3.x, s3.y, s3.z, s3.w};

  f16x8 oa, ob;
#pragma unroll
  for (int e = 0; e < 8; ++e) oa[e] = (_Float16)((float)si[e] * tbl[mi[e]]);
#pragma unroll
  for (int e = 0; e < 8; ++e) ob[e] = (_Float16)((float)si[8 + e] * tbl[mi[8 + e]]);
  *(f16x8*)&Wh[base] = oa;
  *(f16x8*)&Wh[base + 8] = ob;
}

// ---------------------------------------------------------------------------
// x (fp32) -> fp16
// ---------------------------------------------------------------------------
__global__ __launch_bounds__(256) void xconv_kernel(const float* __restrict__ x,
                                                    _Float16* __restrict__ xh) {
  int v = blockIdx.x * 256 + threadIdx.x;
  int base = v * 8;
  float4 a = *(const float4*)(x + base);
  float4 b = *(const float4*)(x + base + 4);
  f16x8 o;
  o[0] = (_Float16)a.x; o[1] = (_Float16)a.y;
  o[2] = (_Float16)a.z; o[3] = (_Float16)a.w;
  o[4] = (_Float16)b.x; o[5] = (_Float16)b.y;
  o[6] = (_Float16)b.z; o[7] = (_Float16)b.w;
  *(f16x8*)&xh[base] = o;
}

// ---------------------------------------------------------------------------
// 128x128 GEMM_BT, BK=32, 3-buffer LDS (48KB), 256 thr = 4 waves (2x2 of
// 64x64), 16x16x32 f16 MFMA.  Occupancy play (r10 diagnosis): 256²/8-wave
// needs ~232 regs/wave -> 2 waves/SIMD -> exactly 1 barrier-group/CU; all
// schedule variants were null because every barrier/drain idles the whole CU.
// Here: ~130 regs/wave + 48KB LDS -> 3 blocks/CU = 3 INDEPENDENT barrier
// groups; one block's drain hides under the other two blocks' MFMA (m97/m114
// mechanism), and counted vmcnt(4) (stage t+2, drain t+1) never hits 0.
// Hazards: read(t) <- staged at t-2, drained at t-1's VMC(4), published by
// t-1's closing BAR; stage over buf[(t+2)%3] is WAR-safe (its readers
// lgkm-retired before the prior BAR).  Swizzle (T2, 0 conflicts r4/r6/r8/r9):
// colbyte ^= ((row>>1)&3)<<4 (row geometry unchanged: 64B rows).
// ---------------------------------------------------------------------------
#define BM 128
#define BN 128
#define BK 32
#define NT (K_DIM / BK)   // 128
#define NBN (N_DIM / BN)  // 86
#define NBM (M_DIM / BM)  // 32

#define BAR() __builtin_amdgcn_s_barrier()
#define LGKM0()                                              \
  asm volatile("s_waitcnt lgkmcnt(0)" ::: "memory");         \
  __builtin_amdgcn_sched_barrier(0)
#define VMC(N) asm volatile("s_waitcnt vmcnt(" #N ")" ::: "memory")

// stage one K32-tile (A 128x32 + B 128x32 = 4 gloads/thread @256thr)
#define STAGE(buf_, ga_, gb_)                                            \
  do {                                                                   \
    gload_lds16((ga_), &lds[buf_][0][wave * 512]);                       \
    gload_lds16((ga_) + 64 * (size_t)K_DIM,                              \
                &lds[buf_][0][2048 + wave * 512]);                       \
    gload_lds16((gb_), &lds[buf_][1][wave * 512]);                       \
    gload_lds16((gb_) + 64 * (size_t)K_DIM,                              \
                &lds[buf_][1][2048 + wave * 512]);                       \
  } while (0)

#define RD_AB(buf_)                                                      \
  do {                                                                   \
    _Pragma("unroll") for (int m = 0; m < 4; ++m)                        \
        af[m] = *(const f16x8*)&lds[buf_][0][aoff + m * 512];            \
    _Pragma("unroll") for (int n = 0; n < 4; ++n)                        \
        bf[n] = *(const f16x8*)&lds[buf_][1][boff + n * 512];            \
  } while (0)

#define MFMA16()                                                         \
  do {                                                                   \
    __builtin_amdgcn_s_setprio(1);                                       \
    _Pragma("unroll") for (int i = 0; i < 4; ++i)                        \
        _Pragma("unroll") for (int j = 0; j < 4; ++j)                    \
            acc[i][j] = __builtin_amdgcn_mfma_f32_16x16x32_f16(          \
                af[i], bf[j], acc[i][j], 0, 0, 0);                       \
    __builtin_amdgcn_s_setprio(0);                                       \
  } while (0)

// one K-tile phase: read cur, stage tile (t+2) into buf stg_, counted drain
#define BODY(cur_, stg_, tn_)                                            \
  do {                                                                   \
    RD_AB(cur_);                                                         \
    STAGE(stg_, gA + (size_t)(tn_)*BK, gB + (size_t)(tn_)*BK);           \
    VMC(4);                                                              \
    BAR();                                                               \
    LGKM0();                                                             \
    MFMA16();                                                            \
    BAR();                                                               \
  } while (0)

__global__ __launch_bounds__(256, 3) void gemm_kernel(
    const _Float16* __restrict__ A, const _Float16* __restrict__ Bt,
    float* __restrict__ C) {
  __shared__ _Float16 lds[3][2][4096];  // 48 KiB

  const int tid = threadIdx.x;
  const int lane = tid & 63;
  const int wave = tid >> 6;  // 0..3
  const int wm = wave >> 1;   // 0..1
  const int wn = wave & 1;    // 0..1

  // XCD-aware swizzle (T1), bn-fastest: 2752 = 8 XCDs x 344 exactly
  const int bid = blockIdx.x;
  const int g = (bid & 7) * 344 + (bid >> 3);
  const int bm = g / NBN;
  const int bn = g - bm * NBN;
  const size_t row0 = (size_t)bm * BM;
  const size_t col0 = (size_t)bn * BN;

  // staging addressing (T2 pre-swizzled source); rows 0..63 (+64 second gload)
  const int sr = tid >> 2;
  const int pcb = (tid & 3) * 16;
  const int cb = pcb ^ (((sr >> 1) & 3) << 4);  // +64 rows: same swizzle bits
  const _Float16* gA = A + (row0 + sr) * (size_t)K_DIM + cb / 2;
  const _Float16* gB = Bt + (col0 + sr) * (size_t)K_DIM + cb / 2;

  // fragment read addressing (16x16x32: row=lane&15, kgrp=lane>>4)
  const int frow = lane & 15;
  const int fpcb = 16 * ((lane >> 4) ^ ((lane >> 1) & 3));
  const int aoff = (wm * 64 + frow) * 32 + fpcb / 2;  // + m*512
  const int boff = (wn * 64 + frow) * 32 + fpcb / 2;  // + n*512

  f32x4 acc[4][4];
#pragma unroll
  for (int m = 0; m < 4; ++m)
#pragma unroll
    for (int n = 0; n < 4; ++n) acc[m][n] = (f32x4)0.0f;

  f16x8 af[4], bf[4];

  // prologue: stage tiles 0,1; drain tile 0
  STAGE(0, gA, gB);
  STAGE(1, gA + BK, gB + BK);
  VMC(4);
  BAR();

  // main loop: t = 0..125 (126 = 3*42), buffers rotate 0,1,2
  for (int t3 = 0; t3 < 126; t3 += 3) {
    BODY(0, 2, t3 + 2);
    BODY(1, 0, t3 + 3);
    BODY(2, 1, t3 + 4);
  }
  // t = 126 (buf 0): no stage; drain tile 127's loads
  RD_AB(0);
  VMC(0);
  BAR();
  LGKM0();
  MFMA16();
  BAR();
  // t = 127 (buf 1)
  RD_AB(1);
  LGKM0();
  MFMA16();

  // epilogue: C/D layout col=lane&15, row=(lane>>4)*4+r
  const int crow = (lane >> 4) * 4;
  const int ccol = lane & 15;
  float* Cw = C + (row0 + wm * 64 + crow) * (size_t)N_DIM + col0 + wn * 64 + ccol;
#pragma unroll
  for (int m = 0; m < 4; ++m)
#pragma unroll
    for (int n = 0; n < 4; ++n)
#pragma unroll
      for (int r = 0; r < 4; ++r)
        Cw[(size_t)(m * 16 + r) * N_DIM + n * 16] = acc[m][n][r];
}

// ---------------------------------------------------------------------------
extern "C" void kernel_launch(void* const* d_in, const int* in_sizes, int n_in,
                              void* d_out, int out_size, void* d_ws, size_t ws_size,
                              hipStream_t stream) {
  const float* x = (const float*)d_in[0];
  const int* Wmag = (const int*)d_in[1];
  const int* Wsgn = (const int*)d_in[2];
  const float* scales = (const float*)d_in[3];
  const float* alphas = (const float*)d_in[4];
  const float* powers = (const float*)d_in[5];
  const float* divisors = (const float*)d_in[6];
  float* out = (float*)d_out;

  _Float16* xh = (_Float16*)d_ws;                        // 32 MB
  _Float16* Wh = xh + (size_t)M_DIM * K_DIM;             // 90 MB

  // 1) dequantize W -> fp16 [N][K]  (per-row LUT, one block per row)
  dequant_kernel<<<N_DIM, 256, 0, stream>>>(
      Wmag, Wsgn, scales, alphas, powers, divisors, Wh);
  // 2) x -> fp16 [M][K]
  {
    int nthreads_total = (M_DIM * K_DIM) / 8;
    xconv_kernel<<<nthreads_total / 256, 256, 0, stream>>>(x, xh);
  }
  // 3) GEMM: [M][K] x [N][K]^T -> [M][N] f32
  {
    dim3 grid(NBM * NBN);  // 32*86 = 2752
    gemm_kernel<<<grid, 256, 0, stream>>>(xh, Wh, out);
  }
}

// Round 12
// 487.198 us; speedup vs baseline: 2.5544x; 1.1950x over previous
//
#include <hip/hip_runtime.h>
#include <hip/hip_bf16.h>
#include <hip/hip_fp16.h>

// Problem constants (reference: OUT=11008, IN=4096, B=2, S=2048)
#define K_DIM 4096
#define N_DIM 11008
#define M_DIM 4096  // B*S

typedef _Float16 f16x8 __attribute__((ext_vector_type(8)));
typedef float f32x4 __attribute__((ext_vector_type(4)));

typedef const __attribute__((address_space(1))) void* gas_cptr;
typedef __attribute__((address_space(3))) void* las_ptr;

__device__ __forceinline__ void gload_lds16(const void* g, void* l) {
  __builtin_amdgcn_global_load_lds((gas_cptr)g, (las_ptr)l, 16, 0, 0);
}

// ---------------------------------------------------------------------------
// Dequant via per-row LUT (r9, proven): 256 curve values per row in LDS,
// then vectorized gather. 16x fewer powf -> memory-bound.
// ---------------------------------------------------------------------------
__global__ __launch_bounds__(256) void dequant_kernel(
    const int* __restrict__ mag, const int* __restrict__ sgn,
    const float* __restrict__ scales, const float* __restrict__ alphas,
    const float* __restrict__ powers, const float* __restrict__ divisors,
    _Float16* __restrict__ Wh) {
  __shared__ float tbl[256];
  const int o = blockIdx.x;   // row
  const int t = threadIdx.x;
  {
    float sc = scales[o];
    float al = alphas[o];
    float p = powers[o];
    float idv = 1.0f / divisors[o];
    float xn = (float)t * idv;
    float pw = __powf(xn, p);  // t==0 -> 0
    tbl[t] = sc * (al * xn + (1.0f - al) * pw);
  }
  __syncthreads();

  const size_t base = (size_t)o * K_DIM + (size_t)t * 16;
  const int4* mp = (const int4*)(mag + base);
  const int4* sp = (const int4*)(sgn + base);
  int4 m0 = mp[0], m1 = mp[1], m2 = mp[2], m3 = mp[3];
  int4 s0 = sp[0], s1 = sp[1], s2 = sp[2], s3 = sp[3];

  int mi[16] = {m0.x, m0.y, m0.z, m0.w, m1.x, m1.y, m1.z, m1.w,
                m2.x, m2.y, m2.z, m2.w, m3.x, m3.y, m3.z, m3.w};
  int si[16] = {s0.x, s0.y, s0.z, s0.w, s1.x, s1.y, s1.z, s1.w,
                s2.x, s2.y, s2.z, s2.w, s3.x, s3.y, s3.z, s3.w};

  f16x8 oa, ob;
#pragma unroll
  for (int e = 0; e < 8; ++e) oa[e] = (_Float16)((float)si[e] * tbl[mi[e]]);
#pragma unroll
  for (int e = 0; e < 8; ++e) ob[e] = (_Float16)((float)si[8 + e] * tbl[mi[8 + e]]);
  *(f16x8*)&Wh[base] = oa;
  *(f16x8*)&Wh[base + 8] = ob;
}

// ---------------------------------------------------------------------------
// x (fp32) -> fp16
// ---------------------------------------------------------------------------
__global__ __launch_bounds__(256) void xconv_kernel(const float* __restrict__ x,
                                                    _Float16* __restrict__ xh) {
  int v = blockIdx.x * 256 + threadIdx.x;
  int base = v * 8;
  float4 a = *(const float4*)(x + base);
  float4 b = *(const float4*)(x + base + 4);
  f16x8 o;
  o[0] = (_Float16)a.x; o[1] = (_Float16)a.y;
  o[2] = (_Float16)a.z; o[3] = (_Float16)a.w;
  o[4] = (_Float16)b.x; o[5] = (_Float16)b.y;
  o[6] = (_Float16)b.z; o[7] = (_Float16)b.w;
  *(f16x8*)&xh[base] = o;
}

// ---------------------------------------------------------------------------
// 256x256 GEMM_BT, BK=64, 512 thr = 8 waves (2x4), 16x16x32 f16 MFMA.
// CROSS-PHASE READ-AHEAD (r12): phase = {read R_{p+1}; stage; [vmc]; s_barrier;
// lgkmcnt(4|8); MFMA_p}.  MFMA waits only the PREVIOUS phase's reads; the
// reads just issued complete DURING the MFMA burst -> LDS pipe and MFMA pipe
// overlap (r11 diagnosis: all prior variants ran them in global alternation =
// sum, 5270 cy/tile vs max 2800).  4 barriers/tile (raw s_barrier: no counter
// drain).  lgkm ledger (12->4/8, DS in-order per wave): ph1 wait4 (R1 done,
// R2 out), ph2 wait8 (R2 done, R3 out), ph3 wait4, ph4 wait8.  vmcnt:
// VMC(4)@ph3 publishes A0B0(t+1) (oldest 4 of 8) for ph4's read-ahead;
// VMC(0)@ph4 covers A1B1(t+1) issued 2 phases (~2600cy) earlier (~free).
// WAR: each region's last reads lgkm-retired >=2 barriers before overwrite.
// Registers alternate 2 A-sets + 2 B-sets (aX/aY/bX/bY) = r8 shape (~104 VGPR,
// 2 waves/SIMD).  Swizzle (T2, 0 conflicts r4/r6/r8/r9/r11):
// colbyte ^= ((row>>1)&3)<<4.
// ---------------------------------------------------------------------------
#define BM 256
#define BN 256
#define BK 64
#define NT (K_DIM / BK)   // 64
#define NBN (N_DIM / BN)  // 43
#define NBM (M_DIM / BM)  // 16

#define BAR() __builtin_amdgcn_s_barrier()
#define SBAR() __builtin_amdgcn_sched_barrier(0)
#define LGKMC(N)                                              \
  asm volatile("s_waitcnt lgkmcnt(" #N ")" ::: "memory");     \
  __builtin_amdgcn_sched_barrier(0)
#define VMC(N) asm volatile("s_waitcnt vmcnt(" #N ")" ::: "memory")

#define STAGE(buf_, reg_, gbase_)                                        \
  do {                                                                   \
    gload_lds16((gbase_), &lds[buf_][reg_][wave * 512]);                 \
    gload_lds16((gbase_) + 128 * (size_t)K_DIM,                          \
                &lds[buf_][reg_][4096 + wave * 512]);                    \
  } while (0)

#define RD_A(dst_, buf_, kh_, qm_)                                       \
  _Pragma("unroll") for (int m = 0; m < 4; ++m)                          \
      dst_[m] = *(const f16x8*)&lds[buf_][kh_][aoff + ((qm_)*4 + m) * 512];

#define RD_B(dst_, buf_, kh_)                                            \
  _Pragma("unroll") for (int n = 0; n < 4; ++n)                          \
      dst_[n] = *(const f16x8*)&lds[buf_][2 + (kh_)][boff + n * 512];

#define MFMA_Q(a_, b_, qm_)                                              \
  do {                                                                   \
    __builtin_amdgcn_s_setprio(1);                                       \
    _Pragma("unroll") for (int i = 0; i < 4; ++i)                        \
        _Pragma("unroll") for (int j = 0; j < 4; ++j)                    \
            acc[(qm_)*4 + i][j] = __builtin_amdgcn_mfma_f32_16x16x32_f16(\
                a_[i], b_[j], acc[(qm_)*4 + i][j], 0, 0, 0);             \
    __builtin_amdgcn_s_setprio(0);                                       \
  } while (0)

__global__ __launch_bounds__(512, 2) void gemm_kernel(
    const _Float16* __restrict__ A, const _Float16* __restrict__ Bt,
    float* __restrict__ C) {
  __shared__ _Float16 lds[2][4][8192];  // 128 KiB; regions: 0=Akh0 1=Akh1 2=Bkh0 3=Bkh1

  const int tid = threadIdx.x;
  const int lane = tid & 63;
  const int wave = tid >> 6;
  const int wm = wave >> 2;  // 0..1
  const int wn = wave & 3;   // 0..3

  // XCD-aware swizzle (T1), bn-fastest (r4-proven): 688 = 8 XCDs x 86
  const int bid = blockIdx.x;
  const int g = (bid & 7) * 86 + (bid >> 3);
  const int bm = g / NBN;
  const int bn = g - bm * NBN;
  const size_t row0 = (size_t)bm * BM;
  const size_t col0 = (size_t)bn * BN;

  // staging addressing (T2 pre-swizzled source)
  const int sr = tid >> 2;
  const int pcb = (tid & 3) * 16;
  const int cb = pcb ^ (((sr >> 1) & 3) << 4);
  const _Float16* gA = A + (row0 + sr) * (size_t)K_DIM + cb / 2;
  const _Float16* gB = Bt + (col0 + sr) * (size_t)K_DIM + cb / 2;

  // fragment read addressing (16x16x32: row=lane&15, kgrp=lane>>4)
  const int frow = lane & 15;
  const int fpcb = 16 * ((lane >> 4) ^ ((lane >> 1) & 3));
  const int aoff = (wm * 128 + frow) * 32 + fpcb / 2;
  const int boff = (wn * 64 + frow) * 32 + fpcb / 2;

  f32x4 acc[8][4];
#pragma unroll
  for (int m = 0; m < 8; ++m)
#pragma unroll
    for (int n = 0; n < 4; ++n) acc[m][n] = (f32x4)0.0f;

  f16x8 aX[4], aY[4], bX[4], bY[4];

  // ---- prologue: stage tile 0, drain, publish, read R1(t=0)
  STAGE(0, 0, gA);
  STAGE(0, 2, gB);
  STAGE(0, 1, gA + 32);
  STAGE(0, 3, gB + 32);
  VMC(0);
  BAR();
  RD_A(aX, 0, 0, 0);   // R1: A-q0-kh0(0)
  RD_B(bX, 0, 0);      //     B-kh0(0)
  SBAR();

  for (int t = 0; t < NT - 1; ++t) {
    const int cur = t & 1;
    const int nxt = cur ^ 1;
    const _Float16* gAn = gA + (size_t)(t + 1) * BK;
    const _Float16* gBn = gB + (size_t)(t + 1) * BK;

    // ph1: MFMA(R1: aX,bX,q0) || read R2 -> aY; stage A0,B0(t+1)
    RD_A(aY, cur, 0, 1);
    SBAR();
    STAGE(nxt, 0, gAn);
    STAGE(nxt, 2, gBn);
    BAR();
    LGKMC(4);
    MFMA_Q(aX, bX, 0);
    // ph2: MFMA(R2: aY,bX,q1) || read R3 -> aX,bY; stage A1,B1(t+1)
    RD_A(aX, cur, 1, 0);
    RD_B(bY, cur, 1);
    SBAR();
    STAGE(nxt, 1, gAn + 32);
    STAGE(nxt, 3, gBn + 32);
    BAR();
    LGKMC(8);
    MFMA_Q(aY, bX, 1);
    // ph3: MFMA(R3: aX,bY,q0) || read R4 -> aY; VMC(4) publishes A0B0(t+1)
    RD_A(aY, cur, 1, 1);
    SBAR();
    VMC(4);
    BAR();
    LGKMC(4);
    MFMA_Q(aX, bY, 0);
    // ph4: MFMA(R4: aY,bY,q1) || read R1'(t+1) -> aX,bX; VMC(0) (~free)
    RD_A(aX, nxt, 0, 0);
    RD_B(bX, nxt, 0);
    SBAR();
    VMC(0);
    BAR();
    LGKMC(8);
    MFMA_Q(aY, bY, 1);
  }

  // ---- tail tile NT-1 (buf 1), no staging, no read-ahead past the end
  {
    // ph1
    RD_A(aY, 1, 0, 1);
    SBAR();
    BAR();
    LGKMC(4);
    MFMA_Q(aX, bX, 0);
    // ph2
    RD_A(aX, 1, 1, 0);
    RD_B(bY, 1, 1);
    SBAR();
    BAR();
    LGKMC(8);
    MFMA_Q(aY, bX, 1);
    // ph3
    RD_A(aY, 1, 1, 1);
    SBAR();
    BAR();
    LGKMC(4);
    MFMA_Q(aX, bY, 0);
    // ph4
    LGKMC(0);
    MFMA_Q(aY, bY, 1);
  }

  // epilogue: C/D layout col=lane&15, row=(lane>>4)*4+r
  const int crow = (lane >> 4) * 4;
  const int ccol = lane & 15;
  float* Cw = C + (row0 + wm * 128 + crow) * (size_t)N_DIM + col0 + wn * 64 + ccol;
#pragma unroll
  for (int m = 0; m < 8; ++m)
#pragma unroll
    for (int n = 0; n < 4; ++n)
#pragma unroll
      for (int r = 0; r < 4; ++r)
        Cw[(size_t)(m * 16 + r) * N_DIM + n * 16] = acc[m][n][r];
}

// ---------------------------------------------------------------------------
extern "C" void kernel_launch(void* const* d_in, const int* in_sizes, int n_in,
                              void* d_out, int out_size, void* d_ws, size_t ws_size,
                              hipStream_t stream) {
  const float* x = (const float*)d_in[0];
  const int* Wmag = (const int*)d_in[1];
  const int* Wsgn = (const int*)d_in[2];
  const float* scales = (const float*)d_in[3];
  const float* alphas = (const float*)d_in[4];
  const float* powers = (const float*)d_in[5];
  const float* divisors = (const float*)d_in[6];
  float* out = (float*)d_out;

  _Float16* xh = (_Float16*)d_ws;                        // 32 MB
  _Float16* Wh = xh + (size_t)M_DIM * K_DIM;             // 90 MB

  // 1) dequantize W -> fp16 [N][K]  (per-row LUT, one block per row)
  dequant_kernel<<<N_DIM, 256, 0, stream>>>(
      Wmag, Wsgn, scales, alphas, powers, divisors, Wh);
  // 2) x -> fp16 [M][K]
  {
    int nthreads_total = (M_DIM * K_DIM) / 8;
    xconv_kernel<<<nthreads_total / 256, 256, 0, stream>>>(x, xh);
  }
  // 3) GEMM: [M][K] x [N][K]^T -> [M][N] f32
  {
    dim3 grid(NBM * NBN);  // 688
    gemm_kernel<<<grid, 512, 0, stream>>>(xh, Wh, out);
  }
}